// Round 4
// baseline (4411.365 us; speedup 1.0000x reference)
//
#include <hip/hip_runtime.h>
#include <hip/hip_fp16.h>

#define B_   32
#define S_   256
#define EMB_ 512
#define H_   1024
#define G4_  4096
#define NL_  5
#define NBLK 256

typedef short bf16x8 __attribute__((ext_vector_type(8)));
typedef float f32x4 __attribute__((ext_vector_type(4)));

__device__ inline unsigned short f2bf(float x) {
  unsigned u = __float_as_uint(x);
  return (unsigned short)((u + 0x7FFF + ((u >> 16) & 1)) >> 16);
}
__device__ inline float bf2f(unsigned short b) {
  return __uint_as_float(((unsigned)b) << 16);
}

// ---------------------------------------------------------------------------
// K0: transpose U [1024][4096] -> Ut [4096][1024] (coalesced both sides).
__global__ __launch_bounds__(256) void k_transpose(const float* __restrict__ U,
                                                   float* __restrict__ Ut) {
  __shared__ float tile[32][33];
  int c0 = blockIdx.x * 32, k0 = blockIdx.y * 32;
  int tx = threadIdx.x & 31, ty = threadIdx.x >> 5;
#pragma unroll
  for (int i = 0; i < 4; ++i)
    tile[ty + 8 * i][tx] = U[(size_t)(k0 + ty + 8 * i) * G4_ + c0 + tx];
  __syncthreads();
#pragma unroll
  for (int i = 0; i < 4; ++i)
    Ut[(size_t)(c0 + ty + 8 * i) * H_ + k0 + tx] = tile[tx][ty + 8 * i];
}

// ---------------------------------------------------------------------------
// K0b: build MFMA-ready B-fragments of U, split bf16 hi/lo.
// Slot (bx, w, s, plane, lane l, j): value U[k][gcol],
//   k = w*256 + s*32 + (l>>4)*8 + j,  n = l&15, gcol = (n&3)*1024 + bx*4 + (n>>2)
// Layout: Ubf[((bx*4+w)*8+s)*128 + plane*64 + l] as bf16x8.
__global__ __launch_bounds__(256) void k_prep(const float* __restrict__ Ut,
                                              bf16x8* __restrict__ Ubf) {
  int gid = blockIdx.x * 256 + threadIdx.x;
  int l = gid & 63;
  int bxws = gid >> 6;
  int n = l & 15, kgrp = l >> 4;
  int s = bxws & 7, bw = bxws >> 3;
  int w = bw & 3, bx = bw >> 2;
  int g = n & 3, ju = n >> 2;
  int gcol = g * 1024 + bx * 4 + ju;
  int kbase = w * 256 + s * 32 + kgrp * 8;
  const float4* f = (const float4*)(Ut + (size_t)gcol * H_ + kbase);
  float4 f0 = f[0], f1 = f[1];
  float v[8] = {f0.x, f0.y, f0.z, f0.w, f1.x, f1.y, f1.z, f1.w};
  bf16x8 vh, vl;
#pragma unroll
  for (int j = 0; j < 8; ++j) {
    unsigned short hi = f2bf(v[j]);
    vh[j] = (short)hi;
    vl[j] = (short)f2bf(v[j] - bf2f(hi));
  }
  Ubf[(size_t)bxws * 128 + l] = vh;
  Ubf[(size_t)bxws * 128 + 64 + l] = vl;
}

// ---------------------------------------------------------------------------
// K1: xz[s][col][b] = sum_e emb[tok[b][s]][e] * W[e][col] + bias[col], fp16 out.
// (unchanged — known good)
__global__ __launch_bounds__(256) void k_xw(const int* __restrict__ tokens,
                                            const float* __restrict__ emb,
                                            const float* __restrict__ W,
                                            const float* __restrict__ bias,
                                            unsigned short* __restrict__ xz) {
  __shared__ int tok_s[32];
  __shared__ float A_lds[32 * 36];
  __shared__ float B_lds[32 * 128];
  __shared__ unsigned short zout[128 * 40];

  int s = blockIdx.y;
  int c0 = blockIdx.x * 128;
  int tid = threadIdx.x;
  if (tid < 32) tok_s[tid] = tokens[tid * S_ + s];

  int tc = tid & 31, tb = tid >> 5;
  int ar = tid >> 3, ap = tid & 7;

  float acc[4][4];
#pragma unroll
  for (int i = 0; i < 4; ++i)
#pragma unroll
    for (int j = 0; j < 4; ++j) acc[i][j] = 0.f;

  for (int kb = 0; kb < 16; ++kb) {
    int k0 = kb * 32;
    __syncthreads();
    {
      const float4 av = *(const float4*)(emb + (size_t)tok_s[ar] * EMB_ + k0 + ap * 4);
      A_lds[(ap * 4 + 0) * 36 + ar] = av.x;
      A_lds[(ap * 4 + 1) * 36 + ar] = av.y;
      A_lds[(ap * 4 + 2) * 36 + ar] = av.z;
      A_lds[(ap * 4 + 3) * 36 + ar] = av.w;
    }
#pragma unroll
    for (int i = 0; i < 4; ++i) {
      int kk = tb + 8 * i;
      float4 bv = *(const float4*)(W + (size_t)(k0 + kk) * G4_ + c0 + 4 * tc);
      *(float4*)(&B_lds[kk * 128 + 4 * tc]) = bv;
    }
    __syncthreads();
#pragma unroll
    for (int kk = 0; kk < 32; ++kk) {
      float a0 = A_lds[kk * 36 + tb];
      float a1 = A_lds[kk * 36 + tb + 8];
      float a2 = A_lds[kk * 36 + tb + 16];
      float a3 = A_lds[kk * 36 + tb + 24];
      float b0 = B_lds[kk * 128 + tc];
      float b1 = B_lds[kk * 128 + tc + 32];
      float b2 = B_lds[kk * 128 + tc + 64];
      float b3 = B_lds[kk * 128 + tc + 96];
      acc[0][0] += a0 * b0; acc[0][1] += a1 * b0; acc[0][2] += a2 * b0; acc[0][3] += a3 * b0;
      acc[1][0] += a0 * b1; acc[1][1] += a1 * b1; acc[1][2] += a2 * b1; acc[1][3] += a3 * b1;
      acc[2][0] += a0 * b2; acc[2][1] += a1 * b2; acc[2][2] += a2 * b2; acc[2][3] += a3 * b2;
      acc[3][0] += a0 * b3; acc[3][1] += a1 * b3; acc[3][2] += a2 * b3; acc[3][3] += a3 * b3;
    }
  }
  __syncthreads();
#pragma unroll
  for (int qc = 0; qc < 4; ++qc) {
    float bv = bias[c0 + tc + 32 * qc];
#pragma unroll
    for (int qb = 0; qb < 4; ++qb) {
      float v = acc[qc][qb] + bv;
      zout[(tc + 32 * qc) * 40 + tb + 8 * qb] = __half_as_ushort(__float2half_rn(v));
    }
  }
  __syncthreads();
  {
    int cc = tid >> 1, hh = (tid & 1) * 16;
    uint4 v0 = *(const uint4*)(&zout[cc * 40 + hh]);
    uint4 v1 = *(const uint4*)(&zout[cc * 40 + hh + 8]);
    unsigned short* dst = xz + ((size_t)s * G4_ + c0 + cc) * 32 + hh;
    *(uint4*)(dst) = v0;
    *(uint4*)(dst + 8) = v1;
  }
}

// ---------------------------------------------------------------------------
// K2: PERSISTENT all-256-steps kernel. grid 256 x 512 (8 waves). Block bx owns
// 4 hidden units (16 gate cols). Wave w = K-slice [w*128,(w+1)*128).
// U frags in registers (loaded once); c in registers; h double-buffered in
// global, exchanged via custom device-scope grid barrier each step.
__global__ __launch_bounds__(512) void k_steps_persist(
    const bf16x8* __restrict__ Ubf,
    const unsigned short* __restrict__ xz,
    unsigned short* __restrict__ h0h, unsigned short* __restrict__ h0l,
    unsigned short* __restrict__ h1h, unsigned short* __restrict__ h1l,
    unsigned* __restrict__ bar) {
  __shared__ float red[8 * 2 * 256];   // [kq][m][pos] partials
  __shared__ float zg[32 * 17];        // [b][n]

  const int tid = threadIdx.x;
  const int bx = blockIdx.x;
  const int u0 = bx * 4;
  const int l = tid & 63, w = tid >> 6;      // wave index = K-slice
  const int bL = l & 15, kg = l >> 4;

  // Preload this wave's U fragments: 4 k-steps x (hi,lo) = 32 VGPRs.
  bf16x8 uh[4], ul[4];
  {
    size_t base = ((size_t)(bx * 4 + (w >> 1)) * 8 + (w & 1) * 4) * 128;
#pragma unroll
    for (int s = 0; s < 4; ++s) {
      uh[s] = Ubf[base + s * 128 + l];
      ul[s] = Ubf[base + s * 128 + 64 + l];
    }
  }

  // z-phase constants (one z per thread)
  const int zm = tid >> 8, zpos = tid & 255;
  const int zrow = zpos >> 4, zn = zpos & 15;
  const int zb = zm * 16 + zrow;
  const int zgcol = (zn & 3) * 1024 + u0 + (zn >> 2);

  // gate-phase constants (threads 0..127: one (b, unit) each); c in register
  const int gb = tid & 31, gj = tid >> 5;
  float creg = 0.f;

  unsigned* cnt = bar;        // arrival counter
  unsigned* epo = bar + 32;   // epoch flag, separate 128B line

  for (int t = 0; t < S_; ++t) {
    const unsigned short* Hhi = (t & 1) ? h0h : h1h;   // read h_{t-1}
    const unsigned short* Hlo = (t & 1) ? h0l : h1l;
    unsigned short* Ohi = (t & 1) ? h1h : h0h;         // write h_t
    unsigned short* Olo = (t & 1) ? h1l : h0l;

    // prefetch xz_t (no h dependency — latency hides under barrier spin)
    float xzv = __half2float(__ushort_as_half(xz[((size_t)t * G4_ + zgcol) * 32 + zb]));

    if (t > 0) {
      if (tid == 0) {
        while (__hip_atomic_load(epo, __ATOMIC_RELAXED, __HIP_MEMORY_SCOPE_AGENT) < (unsigned)t)
          __builtin_amdgcn_s_sleep(1);
        __builtin_amdgcn_fence(__ATOMIC_ACQUIRE, "agent");   // invalidate stale L2 h lines
      }
      __syncthreads();

      f32x4 c0 = {0.f, 0.f, 0.f, 0.f}, c1 = {0.f, 0.f, 0.f, 0.f};
      const bf16x8* Hh8 = (const bf16x8*)Hhi;
      const bf16x8* Hl8 = (const bf16x8*)Hlo;
#pragma unroll
      for (int s = 0; s < 4; ++s) {
        int kidx = w * 16 + s * 4 + kg;
        bf16x8 a0h = Hh8[bL * 128 + kidx];
        bf16x8 a0l = Hl8[bL * 128 + kidx];
        bf16x8 a1h = Hh8[(16 + bL) * 128 + kidx];
        bf16x8 a1l = Hl8[(16 + bL) * 128 + kidx];
        c0 = __builtin_amdgcn_mfma_f32_16x16x32_bf16(a0h, uh[s], c0, 0, 0, 0);
        c1 = __builtin_amdgcn_mfma_f32_16x16x32_bf16(a1h, uh[s], c1, 0, 0, 0);
        c0 = __builtin_amdgcn_mfma_f32_16x16x32_bf16(a0l, uh[s], c0, 0, 0, 0);
        c1 = __builtin_amdgcn_mfma_f32_16x16x32_bf16(a1l, uh[s], c1, 0, 0, 0);
        c0 = __builtin_amdgcn_mfma_f32_16x16x32_bf16(a0h, ul[s], c0, 0, 0, 0);
        c1 = __builtin_amdgcn_mfma_f32_16x16x32_bf16(a1h, ul[s], c1, 0, 0, 0);
      }
#pragma unroll
      for (int r = 0; r < 4; ++r) {
        red[(w * 2 + 0) * 256 + (kg * 4 + r) * 16 + bL] = c0[r];
        red[(w * 2 + 1) * 256 + (kg * 4 + r) * 16 + bL] = c1[r];
      }
    }
    __syncthreads();

    float z = xzv;
    if (t > 0) {
#pragma unroll
      for (int kq = 0; kq < 8; ++kq)
        z += red[(kq * 2 + zm) * 256 + zpos];
    }
    zg[zb * 17 + zn] = z;
    __syncthreads();

    if (tid < 128) {
      float zi = zg[gb * 17 + gj * 4 + 0];
      float zf = zg[gb * 17 + gj * 4 + 1];
      float zc = zg[gb * 17 + gj * 4 + 2];
      float zo = zg[gb * 17 + gj * 4 + 3];
      float ig = 1.f / (1.f + __expf(-zi));
      float fg = 1.f / (1.f + __expf(-zf));
      float gg = tanhf(zc);
      float og = 1.f / (1.f + __expf(-zo));
      creg = fg * creg + ig * gg;
      float hv = og * tanhf(creg);
      unsigned short hh_ = f2bf(hv);
      unsigned short hl_ = f2bf(hv - bf2f(hh_));
      Ohi[gb * H_ + u0 + gj] = hh_;
      Olo[gb * H_ + u0 + gj] = hl_;
    }
    __syncthreads();   // per-wave vmcnt(0) drain: h stores complete in L2
    if (tid == 0) {
      __builtin_amdgcn_fence(__ATOMIC_RELEASE, "agent");   // writeback L2 -> coherent point
      unsigned old = __hip_atomic_fetch_add(cnt, 1u, __ATOMIC_RELAXED, __HIP_MEMORY_SCOPE_AGENT);
      if (old == (unsigned)(NBLK - 1)) {
        __hip_atomic_store(cnt, 0u, __ATOMIC_RELAXED, __HIP_MEMORY_SCOPE_AGENT);
        __hip_atomic_store(epo, (unsigned)(t + 1), __ATOMIC_RELEASE, __HIP_MEMORY_SCOPE_AGENT);
      }
    }
  }
}

// ---------------------------------------------------------------------------
// K3: logits[b][l] = sum_k (hi+lo)[b][k] * Wd[k][l] + bd[l]. grid 5, block 256.
__global__ __launch_bounds__(256) void k_head2(const unsigned short* __restrict__ hh,
                                               const unsigned short* __restrict__ hl,
                                               const float* __restrict__ Wd,
                                               const float* __restrict__ bd,
                                               float* __restrict__ out) {
  __shared__ float red[32 * 9];
  int lbl = blockIdx.x;
  int tid = threadIdx.x;
  int b = tid >> 3, ks = tid & 7;
  float acc = 0.f;
  for (int k = ks * 128; k < ks * 128 + 128; ++k) {
    float hv = bf2f(hh[b * H_ + k]) + bf2f(hl[b * H_ + k]);
    acc += hv * Wd[k * NL_ + lbl];
  }
  red[b * 9 + ks] = acc;
  __syncthreads();
  if (tid < 32) {
    float s = bd[lbl];
#pragma unroll
    for (int i = 0; i < 8; ++i) s += red[tid * 9 + i];
    out[tid * NL_ + lbl] = s;
  }
}

// ---------------------------------------------------------------------------
extern "C" void kernel_launch(void* const* d_in, const int* in_sizes, int n_in,
                              void* d_out, int out_size, void* d_ws, size_t ws_size,
                              hipStream_t stream) {
  const int* tokens  = (const int*)d_in[0];
  const float* emb   = (const float*)d_in[1];
  const float* W     = (const float*)d_in[2];
  const float* U     = (const float*)d_in[3];
  const float* bias  = (const float*)d_in[4];
  const float* Wd    = (const float*)d_in[5];
  const float* bd    = (const float*)d_in[6];
  float* out = (float*)d_out;

  char* ws = (char*)d_ws;
  // Overlaid layout (84,148,480 B total):
  //   Ut fp32 [4096][1024]  @ 0          (16 MB, transient — dead after k_prep)
  //   xz fp16 [256][4096][32] @ 0        (64 MB, written by k_xw AFTER k_prep)
  //   Ubf bf16 frags        @ 67,108,864 (16 MB)
  //   h planes (hi0,lo0,hi1,lo1 bf16 [32][1024]) @ 83,886,080 (4 x 64 KB)
  //   bar (count @+0, epoch @+128) @ 84,148,224 (256 B, zeroed each launch)
  float* Ut          = (float*)ws;
  unsigned short* xz = (unsigned short*)ws;
  bf16x8* Ubf        = (bf16x8*)(ws + 67108864);
  unsigned short* h00 = (unsigned short*)(ws + 83886080);            // buf0 hi
  unsigned short* h01 = (unsigned short*)(ws + 83886080 + 65536);    // buf0 lo
  unsigned short* h10 = (unsigned short*)(ws + 83886080 + 131072);   // buf1 hi
  unsigned short* h11 = (unsigned short*)(ws + 83886080 + 196608);   // buf1 lo
  unsigned* bar      = (unsigned*)(ws + 84148224);

  hipMemsetAsync(bar, 0, 256, stream);
  k_transpose<<<dim3(128, 32), 256, 0, stream>>>(U, Ut);
  k_prep<<<2048, 256, 0, stream>>>(Ut, Ubf);
  k_xw<<<dim3(32, 256), 256, 0, stream>>>(tokens, emb, W, bias, xz);  // clobbers Ut (dead)

  k_steps_persist<<<NBLK, 512, 0, stream>>>(Ubf, xz, h00, h01, h10, h11, bar);

  // t=255 (odd) wrote buf1 (h10/h11)
  k_head2<<<NL_, 256, 0, stream>>>(h10, h11, Wd, bd, out);
}

// Round 5
// 3529.411 us; speedup vs baseline: 1.2499x; 1.2499x over previous
//
#include <hip/hip_runtime.h>
#include <hip/hip_fp16.h>

#define B_   32
#define S_   256
#define EMB_ 512
#define H_   1024
#define G4_  4096
#define NL_  5
#define NBLK 128

typedef short bf16x8 __attribute__((ext_vector_type(8)));
typedef float f32x4 __attribute__((ext_vector_type(4)));
typedef unsigned long long ull;

__device__ inline unsigned short f2bf(float x) {
  unsigned u = __float_as_uint(x);
  return (unsigned short)((u + 0x7FFF + ((u >> 16) & 1)) >> 16);
}
__device__ inline float bf2f(unsigned short b) {
  return __uint_as_float(((unsigned)b) << 16);
}
__device__ inline ull ldq(const ull* p) {
  return __hip_atomic_load(p, __ATOMIC_RELAXED, __HIP_MEMORY_SCOPE_AGENT);
}
__device__ inline void stw(unsigned* p, unsigned v) {
  __hip_atomic_store(p, v, __ATOMIC_RELAXED, __HIP_MEMORY_SCOPE_AGENT);
}

// ---------------------------------------------------------------------------
// K0: transpose U [1024][4096] -> Ut [4096][1024].
__global__ __launch_bounds__(256) void k_transpose(const float* __restrict__ U,
                                                   float* __restrict__ Ut) {
  __shared__ float tile[32][33];
  int c0 = blockIdx.x * 32, k0 = blockIdx.y * 32;
  int tx = threadIdx.x & 31, ty = threadIdx.x >> 5;
#pragma unroll
  for (int i = 0; i < 4; ++i)
    tile[ty + 8 * i][tx] = U[(size_t)(k0 + ty + 8 * i) * G4_ + c0 + tx];
  __syncthreads();
#pragma unroll
  for (int i = 0; i < 4; ++i)
    Ut[(size_t)(c0 + ty + 8 * i) * H_ + k0 + tx] = tile[tx][ty + 8 * i];
}

// ---------------------------------------------------------------------------
// K0b: build MFMA-ready B-fragments of U, split bf16 hi/lo. (unchanged layout)
// frag addr: Ubf[((ug*4 + kslice)*8 + s)*128 + plane*64 + l], ug=0..255 (4 units),
// value U[k][gcol]: k = kslice*256 + s*32 + (l>>4)*8 + j, n=l&15,
// gcol=(n&3)*1024 + ug*4 + (n>>2).
__global__ __launch_bounds__(256) void k_prep(const float* __restrict__ Ut,
                                              bf16x8* __restrict__ Ubf) {
  int gid = blockIdx.x * 256 + threadIdx.x;
  int l = gid & 63;
  int bxws = gid >> 6;
  int n = l & 15, kgrp = l >> 4;
  int s = bxws & 7, bw = bxws >> 3;
  int w = bw & 3, bx = bw >> 2;
  int g = n & 3, ju = n >> 2;
  int gcol = g * 1024 + bx * 4 + ju;
  int kbase = w * 256 + s * 32 + kgrp * 8;
  const float4* f = (const float4*)(Ut + (size_t)gcol * H_ + kbase);
  float4 f0 = f[0], f1 = f[1];
  float v[8] = {f0.x, f0.y, f0.z, f0.w, f1.x, f1.y, f1.z, f1.w};
  bf16x8 vh, vl;
#pragma unroll
  for (int j = 0; j < 8; ++j) {
    unsigned short hi = f2bf(v[j]);
    vh[j] = (short)hi;
    vl[j] = (short)f2bf(v[j] - bf2f(hi));
  }
  Ubf[(size_t)bxws * 128 + l] = vh;
  Ubf[(size_t)bxws * 128 + 64 + l] = vl;
}

// ---------------------------------------------------------------------------
// K1: xz (unchanged — known good)
__global__ __launch_bounds__(256) void k_xw(const int* __restrict__ tokens,
                                            const float* __restrict__ emb,
                                            const float* __restrict__ W,
                                            const float* __restrict__ bias,
                                            unsigned short* __restrict__ xz) {
  __shared__ int tok_s[32];
  __shared__ float A_lds[32 * 36];
  __shared__ float B_lds[32 * 128];
  __shared__ unsigned short zout[128 * 40];

  int s = blockIdx.y;
  int c0 = blockIdx.x * 128;
  int tid = threadIdx.x;
  if (tid < 32) tok_s[tid] = tokens[tid * S_ + s];

  int tc = tid & 31, tb = tid >> 5;
  int ar = tid >> 3, ap = tid & 7;

  float acc[4][4];
#pragma unroll
  for (int i = 0; i < 4; ++i)
#pragma unroll
    for (int j = 0; j < 4; ++j) acc[i][j] = 0.f;

  for (int kb = 0; kb < 16; ++kb) {
    int k0 = kb * 32;
    __syncthreads();
    {
      const float4 av = *(const float4*)(emb + (size_t)tok_s[ar] * EMB_ + k0 + ap * 4);
      A_lds[(ap * 4 + 0) * 36 + ar] = av.x;
      A_lds[(ap * 4 + 1) * 36 + ar] = av.y;
      A_lds[(ap * 4 + 2) * 36 + ar] = av.z;
      A_lds[(ap * 4 + 3) * 36 + ar] = av.w;
    }
#pragma unroll
    for (int i = 0; i < 4; ++i) {
      int kk = tb + 8 * i;
      float4 bv = *(const float4*)(W + (size_t)(k0 + kk) * G4_ + c0 + 4 * tc);
      *(float4*)(&B_lds[kk * 128 + 4 * tc]) = bv;
    }
    __syncthreads();
#pragma unroll
    for (int kk = 0; kk < 32; ++kk) {
      float a0 = A_lds[kk * 36 + tb];
      float a1 = A_lds[kk * 36 + tb + 8];
      float a2 = A_lds[kk * 36 + tb + 16];
      float a3 = A_lds[kk * 36 + tb + 24];
      float b0 = B_lds[kk * 128 + tc];
      float b1 = B_lds[kk * 128 + tc + 32];
      float b2 = B_lds[kk * 128 + tc + 64];
      float b3 = B_lds[kk * 128 + tc + 96];
      acc[0][0] += a0 * b0; acc[0][1] += a1 * b0; acc[0][2] += a2 * b0; acc[0][3] += a3 * b0;
      acc[1][0] += a0 * b1; acc[1][1] += a1 * b1; acc[1][2] += a2 * b1; acc[1][3] += a3 * b1;
      acc[2][0] += a0 * b2; acc[2][1] += a1 * b2; acc[2][2] += a2 * b2; acc[2][3] += a3 * b2;
      acc[3][0] += a0 * b3; acc[3][1] += a1 * b3; acc[3][2] += a2 * b3; acc[3][3] += a3 * b3;
    }
  }
  __syncthreads();
#pragma unroll
  for (int qc = 0; qc < 4; ++qc) {
    float bv = bias[c0 + tc + 32 * qc];
#pragma unroll
    for (int qb = 0; qb < 4; ++qb) {
      float v = acc[qc][qb] + bv;
      zout[(tc + 32 * qc) * 40 + tb + 8 * qb] = __half_as_ushort(__float2half_rn(v));
    }
  }
  __syncthreads();
  {
    int cc = tid >> 1, hh = (tid & 1) * 16;
    uint4 v0 = *(const uint4*)(&zout[cc * 40 + hh]);
    uint4 v1 = *(const uint4*)(&zout[cc * 40 + hh + 8]);
    unsigned short* dst = xz + ((size_t)s * G4_ + c0 + cc) * 32 + hh;
    *(uint4*)(dst) = v0;
    *(uint4*)(dst + 8) = v1;
  }
}

// ---------------------------------------------------------------------------
// K2: persistent steps, FENCE-FREE barrier. grid 128 x 512. Block bx owns 8
// hidden units (unit-groups 2bx, 2bx+1 = 32 gate cols). Wave w = K-slice
// [w*128,(w+1)*128), both unit-groups. h exchanged as packed (hi|lo<<16) uint
// words via relaxed AGENT atomics (write-through / LLC-coherent loads).
// Barrier: non-resetting 2-level counter tree + epoch; no fences anywhere.
__global__ __launch_bounds__(512) void k_steps2(
    const bf16x8* __restrict__ Ubf,
    const unsigned short* __restrict__ xz,
    unsigned* __restrict__ Hh0, unsigned* __restrict__ Hl0,
    unsigned* __restrict__ Hh1, unsigned* __restrict__ Hl1,
    unsigned* __restrict__ bar) {
  __shared__ float red[8192];     // [slot 0..31][lane*4+q]  (32 KB)
  __shared__ float zg[1056];      // [b][c] stride 33

  const int tid = threadIdx.x;
  const int bx = blockIdx.x;
  const int l = tid & 63, w = tid >> 6;
  const int bL = l & 15, kg = l >> 4;

  // Preload U fragments: 2 cg x 4 s x (hi,lo) = 64 VGPRs.
  bf16x8 uh[2][4], ul[2][4];
#pragma unroll
  for (int cg = 0; cg < 2; ++cg) {
    size_t base = ((size_t)((2 * bx + cg) * 4 + (w >> 1)) * 8 + (w & 1) * 4);
#pragma unroll
    for (int s = 0; s < 4; ++s) {
      uh[cg][s] = Ubf[(base + s) * 128 + l];
      ul[cg][s] = Ubf[(base + s) * 128 + 64 + l];
    }
  }

  // z-phase mapping: thread -> (b=zb0, c=zc) and (b=zb0+16, c=zc)
  const int zc = tid & 31, zb0 = tid >> 5;
  const int zgcol = (zc & 3) * 1024 + bx * 8 + (zc >> 4) * 4 + ((zc & 15) >> 2);
  const int zoff = ((zb0 >> 2) * 16 + (zc & 15)) * 4 + (zb0 & 3);
  const int zcg = zc >> 4;

  // gate mapping (threads 0..255): unit j = gj, batch gb
  const int gb = tid & 31, gj = tid >> 5;
  float creg = 0.f;

  unsigned* leaf = bar + (bx >> 3) * 32;   // 16 leaf lines, 8 blocks each
  unsigned* root = bar + 512;
  unsigned* epo  = bar + 544;

  for (int t = 0; t < S_; ++t) {
    const unsigned* HhR = (t & 1) ? Hh0 : Hh1;   // read h_{t-1}
    const unsigned* HlR = (t & 1) ? Hl0 : Hl1;
    unsigned* HhW = (t & 1) ? Hh1 : Hh0;         // write h_t
    unsigned* HlW = (t & 1) ? Hl1 : Hl0;

    float xzv0 = __half2float(__ushort_as_half(xz[((size_t)t * G4_ + zgcol) * 32 + zb0]));
    float xzv1 = __half2float(__ushort_as_half(xz[((size_t)t * G4_ + zgcol) * 32 + zb0 + 16]));

    if (t > 0) {
      if (tid == 0) {
        while (__hip_atomic_load(epo, __ATOMIC_RELAXED, __HIP_MEMORY_SCOPE_AGENT) < (unsigned)t)
          __builtin_amdgcn_s_sleep(1);
      }
      __syncthreads();
      __atomic_signal_fence(__ATOMIC_ACQUIRE);

      const ull* Hh64 = (const ull*)HhR;
      const ull* Hl64 = (const ull*)HlR;
      f32x4 a00 = {0.f,0.f,0.f,0.f}, a01 = {0.f,0.f,0.f,0.f};
      f32x4 a10 = {0.f,0.f,0.f,0.f}, a11 = {0.f,0.f,0.f,0.f};
      const int r0 = bL * 256, r1 = (16 + bL) * 256;   // ull-index row bases
#pragma unroll
      for (int s = 0; s < 4; ++s) {
        int k2 = w * 32 + s * 8 + kg * 2;              // ull offset in row
        union { ull q[2]; bf16x8 v; } f0h, f0l, f1h, f1l;
        f0h.q[0] = ldq(Hh64 + r0 + k2); f0h.q[1] = ldq(Hh64 + r0 + k2 + 1);
        f1h.q[0] = ldq(Hh64 + r1 + k2); f1h.q[1] = ldq(Hh64 + r1 + k2 + 1);
        f0l.q[0] = ldq(Hl64 + r0 + k2); f0l.q[1] = ldq(Hl64 + r0 + k2 + 1);
        f1l.q[0] = ldq(Hl64 + r1 + k2); f1l.q[1] = ldq(Hl64 + r1 + k2 + 1);
        a00 = __builtin_amdgcn_mfma_f32_16x16x32_bf16(f0h.v, uh[0][s], a00, 0, 0, 0);
        a10 = __builtin_amdgcn_mfma_f32_16x16x32_bf16(f1h.v, uh[0][s], a10, 0, 0, 0);
        a00 = __builtin_amdgcn_mfma_f32_16x16x32_bf16(f0l.v, uh[0][s], a00, 0, 0, 0);
        a10 = __builtin_amdgcn_mfma_f32_16x16x32_bf16(f1l.v, uh[0][s], a10, 0, 0, 0);
        a00 = __builtin_amdgcn_mfma_f32_16x16x32_bf16(f0h.v, ul[0][s], a00, 0, 0, 0);
        a10 = __builtin_amdgcn_mfma_f32_16x16x32_bf16(f1h.v, ul[0][s], a10, 0, 0, 0);
        a01 = __builtin_amdgcn_mfma_f32_16x16x32_bf16(f0h.v, uh[1][s], a01, 0, 0, 0);
        a11 = __builtin_amdgcn_mfma_f32_16x16x32_bf16(f1h.v, uh[1][s], a11, 0, 0, 0);
        a01 = __builtin_amdgcn_mfma_f32_16x16x32_bf16(f0l.v, uh[1][s], a01, 0, 0, 0);
        a11 = __builtin_amdgcn_mfma_f32_16x16x32_bf16(f1l.v, uh[1][s], a11, 0, 0, 0);
        a01 = __builtin_amdgcn_mfma_f32_16x16x32_bf16(f0h.v, ul[1][s], a01, 0, 0, 0);
        a11 = __builtin_amdgcn_mfma_f32_16x16x32_bf16(f1h.v, ul[1][s], a11, 0, 0, 0);
      }
      // lane-major b128 writes (conflict-free): slot = (w*2+m)*2+cg
      *(f32x4*)(&red[((w * 2 + 0) * 2 + 0) * 256 + l * 4]) = a00;
      *(f32x4*)(&red[((w * 2 + 0) * 2 + 1) * 256 + l * 4]) = a01;
      *(f32x4*)(&red[((w * 2 + 1) * 2 + 0) * 256 + l * 4]) = a10;
      *(f32x4*)(&red[((w * 2 + 1) * 2 + 1) * 256 + l * 4]) = a11;
    }
    __syncthreads();

    float z0 = xzv0, z1 = xzv1;
    if (t > 0) {
#pragma unroll
      for (int ww = 0; ww < 8; ++ww) {
        z0 += red[((ww * 2 + 0) * 2 + zcg) * 256 + zoff];
        z1 += red[((ww * 2 + 1) * 2 + zcg) * 256 + zoff];
      }
    }
    zg[zb0 * 33 + zc] = z0;
    zg[(zb0 + 16) * 33 + zc] = z1;
    __syncthreads();

    if (tid < 256) {
      int cb = gb * 33 + (gj >> 2) * 16 + (gj & 3) * 4;
      float zi = zg[cb + 0];
      float zf = zg[cb + 1];
      float zc_ = zg[cb + 2];
      float zo = zg[cb + 3];
      float ig = 1.f / (1.f + __expf(-zi));
      float fg = 1.f / (1.f + __expf(-zf));
      float gg = tanhf(zc_);
      float og = 1.f / (1.f + __expf(-zo));
      creg = fg * creg + ig * gg;
      float hv = og * tanhf(creg);
      unsigned short hh_ = f2bf(hv);
      unsigned short hl_ = f2bf(hv - bf2f(hh_));
      unsigned pk = (unsigned)hh_ | ((unsigned)hl_ << 16);
      unsigned other = (unsigned)__shfl_xor((int)pk, 32, 64);   // partner unit j^1
      int widx = gb * 512 + bx * 4 + (gj >> 1);
      if ((gj & 1) == 0)
        stw(HhW + widx, (pk & 0xffffu) | (other << 16));        // hi-plane word
      else
        stw(HlW + widx, (other >> 16) | (pk & 0xffff0000u));    // lo-plane word
    }
    __syncthreads();   // all waves drained vmcnt -> block's h words at LLC
    if (tid == 0) {
      unsigned old = __hip_atomic_fetch_add(leaf, 1u, __ATOMIC_RELAXED, __HIP_MEMORY_SCOPE_AGENT);
      if (old == (unsigned)(t * 8 + 7)) {
        unsigned o2 = __hip_atomic_fetch_add(root, 1u, __ATOMIC_RELAXED, __HIP_MEMORY_SCOPE_AGENT);
        if (o2 == (unsigned)(t * 16 + 15))
          __hip_atomic_store(epo, (unsigned)(t + 1), __ATOMIC_RELAXED, __HIP_MEMORY_SCOPE_AGENT);
      }
    }
  }
}

// ---------------------------------------------------------------------------
// K3: logits from packed h (buf1). grid 5, block 256.
__global__ __launch_bounds__(256) void k_head3(const unsigned* __restrict__ Hh,
                                               const unsigned* __restrict__ Hl,
                                               const float* __restrict__ Wd,
                                               const float* __restrict__ bd,
                                               float* __restrict__ out) {
  __shared__ float red[32 * 9];
  int lbl = blockIdx.x;
  int tid = threadIdx.x;
  int b = tid >> 3, ks = tid & 7;
  float acc = 0.f;
  for (int k = ks * 128; k < ks * 128 + 128; k += 2) {
    unsigned wh = Hh[b * 512 + (k >> 1)];
    unsigned wl = Hl[b * 512 + (k >> 1)];
    float h0 = bf2f((unsigned short)(wh & 0xffffu)) + bf2f((unsigned short)(wl & 0xffffu));
    float h1 = bf2f((unsigned short)(wh >> 16)) + bf2f((unsigned short)(wl >> 16));
    acc += h0 * Wd[k * NL_ + lbl] + h1 * Wd[(k + 1) * NL_ + lbl];
  }
  red[b * 9 + ks] = acc;
  __syncthreads();
  if (tid < 32) {
    float s = bd[lbl];
#pragma unroll
    for (int i = 0; i < 8; ++i) s += red[tid * 9 + i];
    out[tid * NL_ + lbl] = s;
  }
}

// ---------------------------------------------------------------------------
extern "C" void kernel_launch(void* const* d_in, const int* in_sizes, int n_in,
                              void* d_out, int out_size, void* d_ws, size_t ws_size,
                              hipStream_t stream) {
  const int* tokens  = (const int*)d_in[0];
  const float* emb   = (const float*)d_in[1];
  const float* W     = (const float*)d_in[2];
  const float* U     = (const float*)d_in[3];
  const float* bias  = (const float*)d_in[4];
  const float* Wd    = (const float*)d_in[5];
  const float* bd    = (const float*)d_in[6];
  float* out = (float*)d_out;

  char* ws = (char*)d_ws;
  // Overlaid layout:
  //   Ut fp32 [4096][1024]   @ 0          (16 MB, dead after k_prep)
  //   xz fp16 [256][4096][32] @ 0         (64 MB, written by k_xw after k_prep)
  //   Ubf bf16 frags         @ 67,108,864 (16 MB)
  //   packed h: Hh0,Hl0,Hh1,Hl1 (uint [32][512]) @ 83,886,080 (4 x 64 KB)
  //   bar                    @ 84,148,224 (4 KB: 16 leaf lines, root, epoch)
  float* Ut          = (float*)ws;
  unsigned short* xz = (unsigned short*)ws;
  bf16x8* Ubf        = (bf16x8*)(ws + 67108864);
  unsigned* Hh0      = (unsigned*)(ws + 83886080);
  unsigned* Hl0      = (unsigned*)(ws + 83886080 + 65536);
  unsigned* Hh1      = (unsigned*)(ws + 83886080 + 131072);
  unsigned* Hl1      = (unsigned*)(ws + 83886080 + 196608);
  unsigned* bar      = (unsigned*)(ws + 84148224);

  hipMemsetAsync(bar, 0, 4096, stream);
  k_transpose<<<dim3(128, 32), 256, 0, stream>>>(U, Ut);
  k_prep<<<2048, 256, 0, stream>>>(Ut, Ubf);
  k_xw<<<dim3(32, 256), 256, 0, stream>>>(tokens, emb, W, bias, xz);  // clobbers Ut (dead)

  k_steps2<<<NBLK, 512, 0, stream>>>(Ubf, xz, Hh0, Hl0, Hh1, Hl1, bar);

  // t=255 (odd) wrote buf1
  k_head3<<<NL_, 256, 0, stream>>>(Hh1, Hl1, Wd, bd, out);
}

// Round 6
// 2120.454 us; speedup vs baseline: 2.0804x; 1.6645x over previous
//
#include <hip/hip_runtime.h>
#include <hip/hip_fp16.h>

#define B_   32
#define S_   256
#define EMB_ 512
#define H_   1024
#define G4_  4096
#define NL_  5
#define NBLK 64

typedef short bf16x8 __attribute__((ext_vector_type(8)));
typedef float f32x4 __attribute__((ext_vector_type(4)));
typedef unsigned long long ull;

__device__ inline unsigned short f2bf(float x) {
  unsigned u = __float_as_uint(x);
  return (unsigned short)((u + 0x7FFF + ((u >> 16) & 1)) >> 16);
}
__device__ inline float bf2f(unsigned short b) {
  return __uint_as_float(((unsigned)b) << 16);
}
__device__ inline ull ldq(const ull* p) {
  return __hip_atomic_load(p, __ATOMIC_RELAXED, __HIP_MEMORY_SCOPE_AGENT);
}
__device__ inline void stw(unsigned* p, unsigned v) {
  __hip_atomic_store(p, v, __ATOMIC_RELAXED, __HIP_MEMORY_SCOPE_AGENT);
}

// ---------------------------------------------------------------------------
// K0: transpose U [1024][4096] -> Ut [4096][1024].
__global__ __launch_bounds__(256) void k_transpose(const float* __restrict__ U,
                                                   float* __restrict__ Ut) {
  __shared__ float tile[32][33];
  int c0 = blockIdx.x * 32, k0 = blockIdx.y * 32;
  int tx = threadIdx.x & 31, ty = threadIdx.x >> 5;
#pragma unroll
  for (int i = 0; i < 4; ++i)
    tile[ty + 8 * i][tx] = U[(size_t)(k0 + ty + 8 * i) * G4_ + c0 + tx];
  __syncthreads();
#pragma unroll
  for (int i = 0; i < 4; ++i)
    Ut[(size_t)(c0 + ty + 8 * i) * H_ + k0 + tx] = tile[tx][ty + 8 * i];
}

// ---------------------------------------------------------------------------
// K0b: build MFMA-ready B-fragments of U, split bf16 hi/lo. (proven layout)
// Ubf[((ug*4 + kslice)*8 + s8)*128 + plane*64 + l]: value U[k][gcol],
// k = kslice*256 + s8*32 + (l>>4)*8 + j, n16 = l&15,
// gcol = (n16&3)*1024 + ug*4 + (n16>>2).
__global__ __launch_bounds__(256) void k_prep(const float* __restrict__ Ut,
                                              bf16x8* __restrict__ Ubf) {
  int gid = blockIdx.x * 256 + threadIdx.x;
  int l = gid & 63;
  int bxws = gid >> 6;
  int n = l & 15, kgrp = l >> 4;
  int s = bxws & 7, bw = bxws >> 3;
  int w = bw & 3, bx = bw >> 2;
  int g = n & 3, ju = n >> 2;
  int gcol = g * 1024 + bx * 4 + ju;
  int kbase = w * 256 + s * 32 + kgrp * 8;
  const float4* f = (const float4*)(Ut + (size_t)gcol * H_ + kbase);
  float4 f0 = f[0], f1 = f[1];
  float v[8] = {f0.x, f0.y, f0.z, f0.w, f1.x, f1.y, f1.z, f1.w};
  bf16x8 vh, vl;
#pragma unroll
  for (int j = 0; j < 8; ++j) {
    unsigned short hi = f2bf(v[j]);
    vh[j] = (short)hi;
    vl[j] = (short)f2bf(v[j] - bf2f(hi));
  }
  Ubf[(size_t)bxws * 128 + l] = vh;
  Ubf[(size_t)bxws * 128 + 64 + l] = vl;
}

// ---------------------------------------------------------------------------
// K1: xz (unchanged — known good)
__global__ __launch_bounds__(256) void k_xw(const int* __restrict__ tokens,
                                            const float* __restrict__ emb,
                                            const float* __restrict__ W,
                                            const float* __restrict__ bias,
                                            unsigned short* __restrict__ xz) {
  __shared__ int tok_s[32];
  __shared__ float A_lds[32 * 36];
  __shared__ float B_lds[32 * 128];
  __shared__ unsigned short zout[128 * 40];

  int s = blockIdx.y;
  int c0 = blockIdx.x * 128;
  int tid = threadIdx.x;
  if (tid < 32) tok_s[tid] = tokens[tid * S_ + s];

  int tc = tid & 31, tb = tid >> 5;
  int ar = tid >> 3, ap = tid & 7;

  float acc[4][4];
#pragma unroll
  for (int i = 0; i < 4; ++i)
#pragma unroll
    for (int j = 0; j < 4; ++j) acc[i][j] = 0.f;

  for (int kb = 0; kb < 16; ++kb) {
    int k0 = kb * 32;
    __syncthreads();
    {
      const float4 av = *(const float4*)(emb + (size_t)tok_s[ar] * EMB_ + k0 + ap * 4);
      A_lds[(ap * 4 + 0) * 36 + ar] = av.x;
      A_lds[(ap * 4 + 1) * 36 + ar] = av.y;
      A_lds[(ap * 4 + 2) * 36 + ar] = av.z;
      A_lds[(ap * 4 + 3) * 36 + ar] = av.w;
    }
#pragma unroll
    for (int i = 0; i < 4; ++i) {
      int kk = tb + 8 * i;
      float4 bv = *(const float4*)(W + (size_t)(k0 + kk) * G4_ + c0 + 4 * tc);
      *(float4*)(&B_lds[kk * 128 + 4 * tc]) = bv;
    }
    __syncthreads();
#pragma unroll
    for (int kk = 0; kk < 32; ++kk) {
      float a0 = A_lds[kk * 36 + tb];
      float a1 = A_lds[kk * 36 + tb + 8];
      float a2 = A_lds[kk * 36 + tb + 16];
      float a3 = A_lds[kk * 36 + tb + 24];
      float b0 = B_lds[kk * 128 + tc];
      float b1 = B_lds[kk * 128 + tc + 32];
      float b2 = B_lds[kk * 128 + tc + 64];
      float b3 = B_lds[kk * 128 + tc + 96];
      acc[0][0] += a0 * b0; acc[0][1] += a1 * b0; acc[0][2] += a2 * b0; acc[0][3] += a3 * b0;
      acc[1][0] += a0 * b1; acc[1][1] += a1 * b1; acc[1][2] += a2 * b1; acc[1][3] += a3 * b1;
      acc[2][0] += a0 * b2; acc[2][1] += a1 * b2; acc[2][2] += a2 * b2; acc[2][3] += a3 * b2;
      acc[3][0] += a0 * b3; acc[3][1] += a1 * b3; acc[3][2] += a2 * b3; acc[3][3] += a3 * b3;
    }
  }
  __syncthreads();
#pragma unroll
  for (int qc = 0; qc < 4; ++qc) {
    float bv = bias[c0 + tc + 32 * qc];
#pragma unroll
    for (int qb = 0; qb < 4; ++qb) {
      float v = acc[qc][qb] + bv;
      zout[(tc + 32 * qc) * 40 + tb + 8 * qb] = __half_as_ushort(__float2half_rn(v));
    }
  }
  __syncthreads();
  {
    int cc = tid >> 1, hh = (tid & 1) * 16;
    uint4 v0 = *(const uint4*)(&zout[cc * 40 + hh]);
    uint4 v1 = *(const uint4*)(&zout[cc * 40 + hh + 8]);
    unsigned short* dst = xz + ((size_t)s * G4_ + c0 + cc) * 32 + hh;
    *(uint4*)(dst) = v0;
    *(uint4*)(dst + 8) = v1;
  }
}

// ---------------------------------------------------------------------------
// K2: persistent steps v3. grid 64 x 512 (8 waves). Block bx = 16 units
// (unit-groups bx*4..bx*4+3 = 64 gate cols); wave w = K-slice [w*128,(w+1)*128).
// h stored in A-FRAGMENT layout (hi/lo planes):
//   byte addr = m*32768 + kidx*256 + row*16 + j*2   (m=b>>4,row=b&15,kidx=k>>3,j=k&7)
// so a wave's fragment load is base + lane*16B — contiguous 1KB. All h traffic
// via relaxed AGENT atomics (LLC-coherent). Barrier: single non-resetting
// counter + epoch, no fences.
__global__ __launch_bounds__(512, 2) void k_steps3(
    const bf16x8* __restrict__ Ubf,
    const unsigned short* __restrict__ xz,
    unsigned* __restrict__ Hh0, unsigned* __restrict__ Hl0,
    unsigned* __restrict__ Hh1, unsigned* __restrict__ Hl1,
    unsigned* __restrict__ bar) {
  __shared__ float red[64 * 256];   // 64KB: slot = w*8 + m*4 + cg, elem = l*4+r
  __shared__ float zg[32 * 66];     // [b][cg*16+n16]

  const int tid = threadIdx.x;
  const int bx = blockIdx.x;
  const int l = tid & 63, w = tid >> 6;

  // U fragments in registers: [cg][s] hi/lo = 128 VGPRs.
  bf16x8 uh[4][4], ul[4][4];
#pragma unroll
  for (int cg = 0; cg < 4; ++cg) {
    size_t base = ((size_t)(bx * 4 + cg) * 4 + (w >> 1)) * 8 + (w & 1) * 4;
#pragma unroll
    for (int s = 0; s < 4; ++s) {
      uh[cg][s] = Ubf[(base + s) * 128 + l];
      ul[cg][s] = Ubf[(base + s) * 128 + 64 + l];
    }
  }

  // reducer mapping: thread = (zm, zpos=l*4+r) -> z(b=zb, n16=zn16, cg=0..3)
  const int zm = tid >> 8, zpos = tid & 255;
  const int zl = zpos >> 2, zr = zpos & 3;
  const int zn16 = zl & 15;
  const int zb = zm * 16 + (zl >> 4) * 4 + zr;
  int zgcol[4];
#pragma unroll
  for (int cg = 0; cg < 4; ++cg)
    zgcol[cg] = (zn16 & 3) * 1024 + (bx * 4 + cg) * 4 + (zn16 >> 2);

  // gate mapping: thread = (gb=tid&31, gu=tid>>5); unit k = bx*16+gu
  const int gb = tid & 31, gu = tid >> 5;
  const int gk = bx * 16 + gu;
  const int widx = (gb >> 4) * 8192 + (gk >> 3) * 64 + (gb & 15) * 4 + ((gk & 7) >> 1);
  const int zrd = gb * 66 + (gu >> 2) * 16 + (gu & 3) * 4;
  float creg = 0.f;

  unsigned* cnt = bar;
  unsigned* epo = bar + 64;   // separate 256B line

  for (int t = 0; t < S_; ++t) {
    const ull* RdH = (const ull*)((t & 1) ? Hh0 : Hh1);
    const ull* RdL = (const ull*)((t & 1) ? Hl0 : Hl1);
    unsigned* WrH = (t & 1) ? Hh1 : Hh0;
    unsigned* WrL = (t & 1) ? Hl1 : Hl0;

    // prefetch xz_t (independent of h)
    float xzv[4];
#pragma unroll
    for (int cg = 0; cg < 4; ++cg)
      xzv[cg] = __half2float(__ushort_as_half(xz[((size_t)t * G4_ + zgcol[cg]) * 32 + zb]));

    if (t > 0) {
      if (tid == 0) {
        while (__hip_atomic_load(epo, __ATOMIC_RELAXED, __HIP_MEMORY_SCOPE_AGENT) < (unsigned)t)
          __builtin_amdgcn_s_sleep(1);
      }
      __syncthreads();

      f32x4 acc[4][2];
#pragma unroll
      for (int cg = 0; cg < 4; ++cg) {
        acc[cg][0] = (f32x4){0.f, 0.f, 0.f, 0.f};
        acc[cg][1] = (f32x4){0.f, 0.f, 0.f, 0.f};
      }
      union F { ull q[2]; bf16x8 v; };
      F A[2][4];   // [stage][0=m0h,1=m1h,2=m0l,3=m1l]
#define LOADA(st, s)                                                      \
      { int i0 = ((w * 16 + (s) * 4) * 32) + l * 2;                       \
        A[st][0].q[0] = ldq(RdH + i0);        A[st][0].q[1] = ldq(RdH + i0 + 1); \
        A[st][1].q[0] = ldq(RdH + 4096 + i0); A[st][1].q[1] = ldq(RdH + 4096 + i0 + 1); \
        A[st][2].q[0] = ldq(RdL + i0);        A[st][2].q[1] = ldq(RdL + i0 + 1); \
        A[st][3].q[0] = ldq(RdL + 4096 + i0); A[st][3].q[1] = ldq(RdL + 4096 + i0 + 1); }
      LOADA(0, 0)
#pragma unroll
      for (int s = 0; s < 4; ++s) {
        int cur = s & 1;
        if (s < 3) { int nx = cur ^ 1; LOADA(nx, s + 1) }
#pragma unroll
        for (int cg = 0; cg < 4; ++cg) {
          acc[cg][0] = __builtin_amdgcn_mfma_f32_16x16x32_bf16(A[cur][0].v, uh[cg][s], acc[cg][0], 0, 0, 0);
          acc[cg][1] = __builtin_amdgcn_mfma_f32_16x16x32_bf16(A[cur][1].v, uh[cg][s], acc[cg][1], 0, 0, 0);
          acc[cg][0] = __builtin_amdgcn_mfma_f32_16x16x32_bf16(A[cur][2].v, uh[cg][s], acc[cg][0], 0, 0, 0);
          acc[cg][1] = __builtin_amdgcn_mfma_f32_16x16x32_bf16(A[cur][3].v, uh[cg][s], acc[cg][1], 0, 0, 0);
          acc[cg][0] = __builtin_amdgcn_mfma_f32_16x16x32_bf16(A[cur][0].v, ul[cg][s], acc[cg][0], 0, 0, 0);
          acc[cg][1] = __builtin_amdgcn_mfma_f32_16x16x32_bf16(A[cur][1].v, ul[cg][s], acc[cg][1], 0, 0, 0);
        }
      }
#undef LOADA
#pragma unroll
      for (int cg = 0; cg < 4; ++cg) {
        *(f32x4*)(&red[(w * 8 + 0 * 4 + cg) * 256 + l * 4]) = acc[cg][0];
        *(f32x4*)(&red[(w * 8 + 1 * 4 + cg) * 256 + l * 4]) = acc[cg][1];
      }
    }
    __syncthreads();

    // reduce 8 wave-partials + xz -> zg (stride-1 LDS reads, conflict-free)
#pragma unroll
    for (int cg = 0; cg < 4; ++cg) {
      float zz = xzv[cg];
      if (t > 0) {
#pragma unroll
        for (int ww = 0; ww < 8; ++ww)
          zz += red[(ww * 8 + zm * 4 + cg) * 256 + zpos];
      }
      zg[zb * 66 + cg * 16 + zn16] = zz;
    }
    __syncthreads();

    // gates: all 512 threads, one (b, unit) each
    {
      float zi = zg[zrd + 0];
      float zf = zg[zrd + 1];
      float zc_ = zg[zrd + 2];
      float zo = zg[zrd + 3];
      float ig = 1.f / (1.f + __expf(-zi));
      float fg = 1.f / (1.f + __expf(-zf));
      float gg = tanhf(zc_);
      float og = 1.f / (1.f + __expf(-zo));
      creg = fg * creg + ig * gg;
      float hv = og * tanhf(creg);
      unsigned short hh_ = f2bf(hv);
      unsigned short hl_ = f2bf(hv - bf2f(hh_));
      unsigned pk = (unsigned)hh_ | ((unsigned)hl_ << 16);
      unsigned other = (unsigned)__shfl_xor((int)pk, 32, 64);   // partner unit gu^1
      if ((gu & 1) == 0)
        stw(WrH + widx, (pk & 0xffffu) | (other << 16));        // hi-plane word
      else
        stw(WrL + widx, (other >> 16) | (pk & 0xffff0000u));    // lo-plane word
    }
    __syncthreads();   // drains all waves' vmcnt: block's h at LLC
    if (tid == 0) {
      unsigned old = __hip_atomic_fetch_add(cnt, 1u, __ATOMIC_RELAXED, __HIP_MEMORY_SCOPE_AGENT);
      if (old == (unsigned)(t * NBLK + NBLK - 1))
        __hip_atomic_store(epo, (unsigned)(t + 1), __ATOMIC_RELAXED, __HIP_MEMORY_SCOPE_AGENT);
    }
  }
}

// ---------------------------------------------------------------------------
// K3: logits from fragment-layout h. grid 5, block 256.
__global__ __launch_bounds__(256) void k_head4(const unsigned* __restrict__ Hh,
                                               const unsigned* __restrict__ Hl,
                                               const float* __restrict__ Wd,
                                               const float* __restrict__ bd,
                                               float* __restrict__ out) {
  __shared__ float red[32 * 9];
  int lbl = blockIdx.x;
  int tid = threadIdx.x;
  int b = tid >> 3, ks = tid & 7;
  int mb = (b >> 4) * 8192 + (b & 15) * 4;
  float acc = 0.f;
  for (int k = ks * 128; k < ks * 128 + 128; ++k) {
    int idx = mb + (k >> 3) * 64 + ((k & 7) >> 1);
    int sh = (k & 1) * 16;
    float hv = bf2f((unsigned short)((Hh[idx] >> sh) & 0xffffu)) +
               bf2f((unsigned short)((Hl[idx] >> sh) & 0xffffu));
    acc += hv * Wd[k * NL_ + lbl];
  }
  red[b * 9 + ks] = acc;
  __syncthreads();
  if (tid < 32) {
    float s = bd[lbl];
#pragma unroll
    for (int i = 0; i < 8; ++i) s += red[tid * 9 + i];
    out[tid * NL_ + lbl] = s;
  }
}

// ---------------------------------------------------------------------------
extern "C" void kernel_launch(void* const* d_in, const int* in_sizes, int n_in,
                              void* d_out, int out_size, void* d_ws, size_t ws_size,
                              hipStream_t stream) {
  const int* tokens  = (const int*)d_in[0];
  const float* emb   = (const float*)d_in[1];
  const float* W     = (const float*)d_in[2];
  const float* U     = (const float*)d_in[3];
  const float* bias  = (const float*)d_in[4];
  const float* Wd    = (const float*)d_in[5];
  const float* bd    = (const float*)d_in[6];
  float* out = (float*)d_out;

  char* ws = (char*)d_ws;
  // Overlaid layout:
  //   Ut fp32 [4096][1024]   @ 0          (16 MB, dead after k_prep)
  //   xz fp16 [256][4096][32] @ 0         (64 MB, written by k_xw after k_prep)
  //   Ubf bf16 frags         @ 67,108,864 (16 MB)
  //   frag-layout h planes: Hh0,Hl0,Hh1,Hl1 (64 KB each) @ 83,886,080
  //   bar                    @ 84,148,224 (4 KB: counter @+0, epoch @+256B)
  float* Ut          = (float*)ws;
  unsigned short* xz = (unsigned short*)ws;
  bf16x8* Ubf        = (bf16x8*)(ws + 67108864);
  unsigned* Hh0      = (unsigned*)(ws + 83886080);
  unsigned* Hl0      = (unsigned*)(ws + 83886080 + 65536);
  unsigned* Hh1      = (unsigned*)(ws + 83886080 + 131072);
  unsigned* Hl1      = (unsigned*)(ws + 83886080 + 196608);
  unsigned* bar      = (unsigned*)(ws + 84148224);

  hipMemsetAsync(bar, 0, 4096, stream);
  k_transpose<<<dim3(128, 32), 256, 0, stream>>>(U, Ut);
  k_prep<<<2048, 256, 0, stream>>>(Ut, Ubf);
  k_xw<<<dim3(32, 256), 256, 0, stream>>>(tokens, emb, W, bias, xz);  // clobbers Ut (dead)

  k_steps3<<<NBLK, 512, 0, stream>>>(Ubf, xz, Hh0, Hl0, Hh1, Hl1, bar);

  // t=255 (odd) wrote buf1
  k_head4<<<NL_, 256, 0, stream>>>(Hh1, Hl1, Wd, bd, out);
}